// Round 1
// baseline (743.957 us; speedup 1.0000x reference)
//
#include <hip/hip_runtime.h>

#define F_IN 256
#define HID 16
#define NCLS 8

// ---------------- degree count (in-degree via dst; self-loop added later) ----
__global__ void k_deg(const int* __restrict__ dst, int e, unsigned* __restrict__ cnt) {
    int j = blockIdx.x * blockDim.x + threadIdx.x;
    if (j < e) atomicAdd(&cnt[dst[j]], 1u);
}

__global__ void k_dinv(const unsigned* __restrict__ cnt, float* __restrict__ dinv, int n) {
    int i = blockIdx.x * blockDim.x + threadIdx.x;
    if (i < n) dinv[i] = rsqrtf((float)(cnt[i] + 1u));  // deg >= 1 (self loop)
}

// ---------------- GEMM1: t1[n,16] = x[n,256] @ W1[256,16] --------------------
// 16 threads per row (one per output col), W1 staged in LDS, float4 row loads.
__global__ void __launch_bounds__(256) k_gemm1(const float* __restrict__ x,
                                               const float* __restrict__ W1,
                                               float* __restrict__ t1, int n) {
    __shared__ float ws[F_IN * HID];  // 16 KB
    for (int i = threadIdx.x; i < F_IN * HID; i += blockDim.x) ws[i] = W1[i];
    __syncthreads();
    int r = blockIdx.x * 16 + (threadIdx.x >> 4);
    int k = threadIdx.x & 15;
    if (r >= n) return;
    const float4* xr = (const float4*)(x + (size_t)r * F_IN);
    float acc = 0.f;
#pragma unroll 8
    for (int c4 = 0; c4 < F_IN / 4; ++c4) {
        float4 v = xr[c4];
        int c = c4 * 4;
        acc += v.x * ws[(c + 0) * HID + k] + v.y * ws[(c + 1) * HID + k] +
               v.z * ws[(c + 2) * HID + k] + v.w * ws[(c + 3) * HID + k];
    }
    t1[(size_t)r * HID + k] = acc;
}

// ---------------- edge scatter, width 16 -------------------------------------
__global__ void k_agg16(const int* __restrict__ src, const int* __restrict__ dst,
                        const float* __restrict__ dinv, const float* __restrict__ t,
                        float* __restrict__ agg, int e) {
    long gid = (long)blockIdx.x * blockDim.x + threadIdx.x;
    if (gid >= (long)e * HID) return;
    int j = (int)(gid >> 4);
    int k = (int)(gid & 15);
    int s = src[j], d = dst[j];
    float w = dinv[s] * dinv[d];
    atomicAdd(&agg[(long)d * HID + k], w * t[(long)s * HID + k]);
}

// ---------------- post conv1: bias+ReLU, then GEMM2 (16->8) ------------------
__global__ void __launch_bounds__(256) k_post1(const float* __restrict__ agg1,
                                               const float* __restrict__ t1,
                                               const float* __restrict__ dinv,
                                               const float* __restrict__ b1,
                                               const float* __restrict__ W2,
                                               float* __restrict__ t2, int n) {
    __shared__ float w2s[HID * NCLS];
    __shared__ float b1s[HID];
    if (threadIdx.x < HID * NCLS) w2s[threadIdx.x] = W2[threadIdx.x];
    if (threadIdx.x < HID) b1s[threadIdx.x] = b1[threadIdx.x];
    __syncthreads();
    int i = blockIdx.x * blockDim.x + threadIdx.x;
    if (i >= n) return;
    float di = dinv[i];
    float self = di * di;
    float h[HID];
    const float4* a4 = (const float4*)(agg1 + (size_t)i * HID);
    const float4* t4 = (const float4*)(t1 + (size_t)i * HID);
#pragma unroll
    for (int q = 0; q < 4; ++q) {
        float4 a = a4[q], t = t4[q];
        h[q * 4 + 0] = fmaxf(a.x + self * t.x + b1s[q * 4 + 0], 0.f);
        h[q * 4 + 1] = fmaxf(a.y + self * t.y + b1s[q * 4 + 1], 0.f);
        h[q * 4 + 2] = fmaxf(a.z + self * t.z + b1s[q * 4 + 2], 0.f);
        h[q * 4 + 3] = fmaxf(a.w + self * t.w + b1s[q * 4 + 3], 0.f);
    }
    float o[NCLS];
#pragma unroll
    for (int c = 0; c < NCLS; ++c) o[c] = 0.f;
#pragma unroll
    for (int k = 0; k < HID; ++k)
#pragma unroll
        for (int c = 0; c < NCLS; ++c) o[c] += h[k] * w2s[k * NCLS + c];
    float4* o4 = (float4*)(t2 + (size_t)i * NCLS);
    o4[0] = make_float4(o[0], o[1], o[2], o[3]);
    o4[1] = make_float4(o[4], o[5], o[6], o[7]);
}

// ---------------- edge scatter, width 8 --------------------------------------
__global__ void k_agg8(const int* __restrict__ src, const int* __restrict__ dst,
                       const float* __restrict__ dinv, const float* __restrict__ t,
                       float* __restrict__ agg, int e) {
    long gid = (long)blockIdx.x * blockDim.x + threadIdx.x;
    if (gid >= (long)e * NCLS) return;
    int j = (int)(gid >> 3);
    int k = (int)(gid & 7);
    int s = src[j], d = dst[j];
    float w = dinv[s] * dinv[d];
    atomicAdd(&agg[(long)d * NCLS + k], w * t[(long)s * NCLS + k]);
}

// ---------------- post conv2 + mean-pool accumulate --------------------------
__global__ void __launch_bounds__(256) k_post2(const float* __restrict__ agg2,
                                               const float* __restrict__ t2,
                                               const float* __restrict__ dinv,
                                               const float* __restrict__ b2,
                                               const int* __restrict__ batch,
                                               float* __restrict__ out,
                                               float* __restrict__ cg, int n) {
    __shared__ float b2s[NCLS];
    if (threadIdx.x < NCLS) b2s[threadIdx.x] = b2[threadIdx.x];
    __syncthreads();
    int i = blockIdx.x * blockDim.x + threadIdx.x;
    if (i >= n) return;
    float di = dinv[i];
    float self = di * di;
    int g = batch[i];
#pragma unroll
    for (int c = 0; c < NCLS; ++c) {
        float v = agg2[(size_t)i * NCLS + c] + self * t2[(size_t)i * NCLS + c] + b2s[c];
        atomicAdd(&out[g * NCLS + c], v);
    }
    atomicAdd(&cg[g], 1.0f);
}

__global__ void k_div(float* __restrict__ out, const float* __restrict__ cg, int total) {
    int i = blockIdx.x * blockDim.x + threadIdx.x;
    if (i < total) out[i] /= fmaxf(cg[i / NCLS], 1.0f);
}

extern "C" void kernel_launch(void* const* d_in, const int* in_sizes, int n_in,
                              void* d_out, int out_size, void* d_ws, size_t ws_size,
                              hipStream_t stream) {
    const float* x = (const float*)d_in[0];
    const int* ei = (const int*)d_in[1];
    const int* batch = (const int*)d_in[2];
    const float* W1 = (const float*)d_in[4];
    const float* b1 = (const float*)d_in[5];
    const float* W2 = (const float*)d_in[6];
    const float* b2 = (const float*)d_in[7];

    int n = in_sizes[0] / F_IN;
    int e = in_sizes[1] / 2;
    int g = out_size / NCLS;
    const int* src = ei;
    const int* dst = ei + e;

    char* w = (char*)d_ws;
    unsigned* degc = (unsigned*)w; w += (size_t)n * 4;
    float* dinv = (float*)w;       w += (size_t)n * 4;
    float* t1 = (float*)w;         w += (size_t)n * HID * 4;
    float* agg1 = (float*)w;       w += (size_t)n * HID * 4;
    float* t2 = (float*)w;         w += (size_t)n * NCLS * 4;
    float* agg2 = (float*)w;       w += (size_t)n * NCLS * 4;
    float* cg = (float*)w;         w += (size_t)g * 4;

    hipMemsetAsync(degc, 0, (size_t)n * 4, stream);
    hipMemsetAsync(agg1, 0, (size_t)n * HID * 4, stream);
    hipMemsetAsync(agg2, 0, (size_t)n * NCLS * 4, stream);
    hipMemsetAsync(cg, 0, (size_t)g * 4, stream);
    hipMemsetAsync(d_out, 0, (size_t)out_size * 4, stream);

    const int B = 256;
    k_deg<<<(e + B - 1) / B, B, 0, stream>>>(dst, e, degc);
    k_dinv<<<(n + B - 1) / B, B, 0, stream>>>(degc, dinv, n);
    k_gemm1<<<(n + 15) / 16, 256, 0, stream>>>(x, W1, t1, n);
    long tot16 = (long)e * HID;
    k_agg16<<<(unsigned)((tot16 + B - 1) / B), B, 0, stream>>>(src, dst, dinv, t1, agg1, e);
    k_post1<<<(n + B - 1) / B, B, 0, stream>>>(agg1, t1, dinv, b1, W2, t2, n);
    long tot8 = (long)e * NCLS;
    k_agg8<<<(unsigned)((tot8 + B - 1) / B), B, 0, stream>>>(src, dst, dinv, t2, agg2, e);
    k_post2<<<(n + B - 1) / B, B, 0, stream>>>(agg2, t2, dinv, b2, batch, (float*)d_out, cg, n);
    k_div<<<(out_size + B - 1) / B, B, 0, stream>>>((float*)d_out, cg, out_size);
}

// Round 2
// 527.238 us; speedup vs baseline: 1.4110x; 1.4110x over previous
//
#include <hip/hip_runtime.h>

#define F_IN 256
#define HID 16
#define NCLS 8
#define WIN 8

// ---------- degree (in-degree; self-loop accounted as +1 later) --------------
__global__ void k_deg(const int* __restrict__ dst, int e, unsigned* __restrict__ cnt) {
    int j = blockIdx.x * blockDim.x + threadIdx.x;
    if (j < e) atomicAdd(&cnt[dst[j]], 1u);
}

__global__ void k_dinv(const unsigned* __restrict__ cnt, float* __restrict__ dinv, int n) {
    int i = blockIdx.x * blockDim.x + threadIdx.x;
    if (i < n) dinv[i] = rsqrtf((float)(cnt[i] + 1u));
}

// ---------- prefix-sum (3-phase) over degree -> CSR offsets ------------------
__global__ void __launch_bounds__(256) k_bsum(const unsigned* __restrict__ deg,
                                              unsigned* __restrict__ bsum, int n) {
    __shared__ unsigned s[256];
    int i = blockIdx.x * 256 + threadIdx.x;
    s[threadIdx.x] = (i < n) ? deg[i] : 0u;
    __syncthreads();
    for (int st = 128; st > 0; st >>= 1) {
        if (threadIdx.x < st) s[threadIdx.x] += s[threadIdx.x + st];
        __syncthreads();
    }
    if (threadIdx.x == 0) bsum[blockIdx.x] = s[0];
}

__global__ void __launch_bounds__(512) k_scan_bsum(unsigned* __restrict__ bsum, int nb) {
    __shared__ unsigned s[512];
    int t = threadIdx.x;
    unsigned v0 = (t < nb) ? bsum[t] : 0u;
    s[t] = v0;
    __syncthreads();
    for (int off = 1; off < 512; off <<= 1) {
        unsigned v = (t >= off) ? s[t - off] : 0u;
        __syncthreads();
        s[t] += v;
        __syncthreads();
    }
    if (t < nb) bsum[t] = s[t] - v0;  // exclusive
}

__global__ void __launch_bounds__(256) k_offsets(const unsigned* __restrict__ deg,
                                                 const unsigned* __restrict__ bsum,
                                                 unsigned* __restrict__ off, int n) {
    __shared__ unsigned s[256];
    int t = threadIdx.x;
    int i = blockIdx.x * 256 + t;
    unsigned v0 = (i < n) ? deg[i] : 0u;
    s[t] = v0;
    __syncthreads();
    for (int o = 1; o < 256; o <<= 1) {
        unsigned v = (t >= o) ? s[t - o] : 0u;
        __syncthreads();
        s[t] += v;
        __syncthreads();
    }
    if (i < n) off[i] = bsum[blockIdx.x] + s[t] - v0;
    if (i == n - 1) off[n] = bsum[blockIdx.x] + s[t];  // total = e
}

// ---------- CSR bucket fill --------------------------------------------------
__global__ void k_fill(const int* __restrict__ src, const int* __restrict__ dst,
                       const unsigned* __restrict__ off, unsigned* __restrict__ cur,
                       int* __restrict__ csr, int e) {
    int j = blockIdx.x * blockDim.x + threadIdx.x;
    if (j < e) {
        int d = dst[j];
        unsigned p = off[d] + atomicAdd(&cur[d], 1u);
        csr[p] = src[j];
    }
}

// ---------- GEMM1: t1w[n,16] = (x @ W1) * dinv[row] --------------------------
__global__ void __launch_bounds__(256) k_gemm1(const float* __restrict__ x,
                                               const float* __restrict__ W1,
                                               const float* __restrict__ dinv,
                                               float* __restrict__ t1w, int n) {
    __shared__ float ws[HID][260];  // transposed, padded: 2-way bank alias (free)
    for (int idx = threadIdx.x; idx < F_IN * HID; idx += 256) {
        int c = idx >> 4, k = idx & 15;
        ws[k][c] = W1[idx];
    }
    __syncthreads();
    int r = blockIdx.x * 16 + (threadIdx.x >> 4);
    int k = threadIdx.x & 15;
    if (r >= n) return;
    const float4* xr = (const float4*)(x + (size_t)r * F_IN);
    const float4* wr = (const float4*)&ws[k][0];  // k*1040B, 16B-aligned
    float acc = 0.f;
#pragma unroll 8
    for (int c4 = 0; c4 < F_IN / 4; ++c4) {
        float4 v = xr[c4], w = wr[c4];
        acc += v.x * w.x + v.y * w.y + v.z * w.z + v.w * w.w;
    }
    t1w[(size_t)r * HID + k] = acc * dinv[r];
}

// ---------- conv1 aggregation (gather) + bias + ReLU -------------------------
// h[d,k] = relu( dinv[d] * (sum_{s in N(d)} t1w[s,k] + t1w[d,k]) + b1[k] )
__global__ void __launch_bounds__(256) k_agg16(const int* __restrict__ csr,
                                               const unsigned* __restrict__ off,
                                               const float* __restrict__ t1w,
                                               const float* __restrict__ dinv,
                                               const float* __restrict__ b1,
                                               float* __restrict__ h, int n) {
    __shared__ float b1s[HID];
    if (threadIdx.x < HID) b1s[threadIdx.x] = b1[threadIdx.x];
    __syncthreads();
    int d = blockIdx.x * 16 + (threadIdx.x >> 4);
    int k = threadIdx.x & 15;
    if (d >= n) return;
    unsigned p = off[d], pe = off[d + 1];
    float acc = t1w[(size_t)d * HID + k];  // self loop
    for (; p + 1 < pe; p += 2) {
        int s0 = csr[p], s1 = csr[p + 1];
        float v0 = t1w[(size_t)s0 * HID + k];
        float v1 = t1w[(size_t)s1 * HID + k];
        acc += v0 + v1;
    }
    if (p < pe) acc += t1w[(size_t)csr[p] * HID + k];
    h[(size_t)d * HID + k] = fmaxf(acc * dinv[d] + b1s[k], 0.f);
}

// ---------- GEMM2: t2w[n,8] = (h @ W2) * dinv[row] ---------------------------
__global__ void __launch_bounds__(256) k_gemm2(const float* __restrict__ h,
                                               const float* __restrict__ W2,
                                               const float* __restrict__ dinv,
                                               float* __restrict__ t2w, int n) {
    __shared__ float w2s[HID * NCLS];
    if (threadIdx.x < HID * NCLS) w2s[threadIdx.x] = W2[threadIdx.x];
    __syncthreads();
    int i = blockIdx.x * blockDim.x + threadIdx.x;
    if (i >= n) return;
    float hv[HID];
    const float4* h4 = (const float4*)(h + (size_t)i * HID);
#pragma unroll
    for (int q = 0; q < 4; ++q) {
        float4 v = h4[q];
        hv[q * 4 + 0] = v.x; hv[q * 4 + 1] = v.y;
        hv[q * 4 + 2] = v.z; hv[q * 4 + 3] = v.w;
    }
    float o[NCLS];
#pragma unroll
    for (int c = 0; c < NCLS; ++c) o[c] = 0.f;
#pragma unroll
    for (int k = 0; k < HID; ++k)
#pragma unroll
        for (int c = 0; c < NCLS; ++c) o[c] += hv[k] * w2s[k * NCLS + c];
    float di = dinv[i];
    float4* o4 = (float4*)(t2w + (size_t)i * NCLS);
    o4[0] = make_float4(o[0] * di, o[1] * di, o[2] * di, o[3] * di);
    o4[1] = make_float4(o[4] * di, o[5] * di, o[6] * di, o[7] * di);
}

// ---------- conv2 aggregation (gather) + bias + fused mean-pool accumulate ---
__global__ void __launch_bounds__(256) k_agg8pool(const int* __restrict__ csr,
                                                  const unsigned* __restrict__ off,
                                                  const float* __restrict__ t2w,
                                                  const float* __restrict__ dinv,
                                                  const float* __restrict__ b2,
                                                  const int* __restrict__ batch,
                                                  float* __restrict__ out,
                                                  float* __restrict__ cg, int n) {
    __shared__ float wacc[WIN][NCLS];
    __shared__ float wcnt[WIN];
    __shared__ int gbase_s;
    int t = threadIdx.x;
    if (t < WIN * NCLS) ((float*)wacc)[t] = 0.f;
    if (t < WIN) wcnt[t] = 0.f;
    int b0 = blockIdx.x * 32;  // 32 dsts per block, 8 lanes each
    if (t == 0) gbase_s = batch[b0 < n ? b0 : (n - 1)];
    __syncthreads();
    int d = b0 + (t >> 3);
    int k = t & 7;
    int gbase = gbase_s;
    if (d < n) {
        unsigned p = off[d], pe = off[d + 1];
        float acc = t2w[(size_t)d * NCLS + k];  // self loop
        for (; p + 1 < pe; p += 2) {
            int s0 = csr[p], s1 = csr[p + 1];
            float v0 = t2w[(size_t)s0 * NCLS + k];
            float v1 = t2w[(size_t)s1 * NCLS + k];
            acc += v0 + v1;
        }
        if (p < pe) acc += t2w[(size_t)csr[p] * NCLS + k];
        float v = acc * dinv[d] + b2[k];
        int g = batch[d];
        if (g - gbase < WIN) {  // batch sorted => g >= gbase
            atomicAdd(&wacc[g - gbase][k], v);
            if (k == 0) atomicAdd(&wcnt[g - gbase], 1.f);
        } else {  // window overflow (tiny graphs) — rare fallback
            atomicAdd(&out[(size_t)g * NCLS + k], v);
            if (k == 0) atomicAdd(&cg[g], 1.f);
        }
    }
    __syncthreads();
    if (t < WIN * NCLS) {
        int gg = t >> 3, kk = t & 7;
        if (wcnt[gg] > 0.f) atomicAdd(&out[(size_t)(gbase + gg) * NCLS + kk], wacc[gg][kk]);
    }
    if (t < WIN && wcnt[t] > 0.f) atomicAdd(&cg[gbase + t], wcnt[t]);
}

__global__ void k_div(float* __restrict__ out, const float* __restrict__ cg, int total) {
    int i = blockIdx.x * blockDim.x + threadIdx.x;
    if (i < total) out[i] /= fmaxf(cg[i / NCLS], 1.0f);
}

extern "C" void kernel_launch(void* const* d_in, const int* in_sizes, int n_in,
                              void* d_out, int out_size, void* d_ws, size_t ws_size,
                              hipStream_t stream) {
    const float* x = (const float*)d_in[0];
    const int* ei = (const int*)d_in[1];
    const int* batch = (const int*)d_in[2];
    const float* W1 = (const float*)d_in[4];
    const float* b1 = (const float*)d_in[5];
    const float* W2 = (const float*)d_in[6];
    const float* b2 = (const float*)d_in[7];

    int n = in_sizes[0] / F_IN;
    int e = in_sizes[1] / 2;
    int g = out_size / NCLS;
    const int* src = ei;
    const int* dst = ei + e;
    int nb = (n + 255) / 256;

    char* w = (char*)d_ws;
    unsigned* degc = (unsigned*)w; w += (size_t)n * 4;
    unsigned* cur  = (unsigned*)w; w += (size_t)n * 4;
    float* dinv    = (float*)w;    w += (size_t)n * 4;
    unsigned* off  = (unsigned*)w; w += ((size_t)n + 1) * 4;
    unsigned* bsum = (unsigned*)w; w += (size_t)512 * 4;
    float* t1w     = (float*)w;    w += (size_t)n * HID * 4;
    float* hbuf    = (float*)w;    w += (size_t)n * HID * 4;
    float* t2w     = (float*)w;    w += (size_t)n * NCLS * 4;
    float* cg      = (float*)w;    w += (size_t)g * 4;
    int* csr       = (int*)w;      w += (size_t)e * 4;

    hipMemsetAsync(degc, 0, (size_t)n * 4, stream);
    hipMemsetAsync(cur, 0, (size_t)n * 4, stream);
    hipMemsetAsync(cg, 0, (size_t)g * 4, stream);
    hipMemsetAsync(d_out, 0, (size_t)out_size * 4, stream);

    const int B = 256;
    k_deg<<<(e + B - 1) / B, B, 0, stream>>>(dst, e, degc);
    k_bsum<<<nb, 256, 0, stream>>>(degc, bsum, n);
    k_scan_bsum<<<1, 512, 0, stream>>>(bsum, nb);
    k_offsets<<<nb, 256, 0, stream>>>(degc, bsum, off, n);
    k_dinv<<<(n + B - 1) / B, B, 0, stream>>>(degc, dinv, n);
    k_fill<<<(e + B - 1) / B, B, 0, stream>>>(src, dst, off, cur, csr, e);
    k_gemm1<<<(n + 15) / 16, 256, 0, stream>>>(x, W1, dinv, t1w, n);
    k_agg16<<<(n + 15) / 16, 256, 0, stream>>>(csr, off, t1w, dinv, b1, hbuf, n);
    k_gemm2<<<(n + B - 1) / B, B, 0, stream>>>(hbuf, W2, dinv, t2w, n);
    k_agg8pool<<<(n + 31) / 32, 256, 0, stream>>>(csr, off, t2w, dinv, b2, batch,
                                                  (float*)d_out, cg, n);
    k_div<<<(out_size + B - 1) / B, B, 0, stream>>>((float*)d_out, cg, out_size);
}

// Round 3
// 527.152 us; speedup vs baseline: 1.4113x; 1.0002x over previous
//
#include <hip/hip_runtime.h>

#define F_IN 256
#define HID 16
#define NCLS 8
#define WIN 8

typedef float f4v __attribute__((ext_vector_type(4)));

// ---------- degree (in-degree; self-loop accounted as +1 later) --------------
__global__ void k_deg(const int* __restrict__ dst, int e, unsigned* __restrict__ cnt) {
    int j = blockIdx.x * blockDim.x + threadIdx.x;
    if (j < e) {
        int d = __builtin_nontemporal_load(&dst[j]);
        atomicAdd(&cnt[d], 1u);
    }
}

// ---------- prefix-sum (3-phase) over degree -> CSR offsets ------------------
__global__ void __launch_bounds__(256) k_bsum(const unsigned* __restrict__ deg,
                                              unsigned* __restrict__ bsum, int n) {
    __shared__ unsigned s[256];
    int i = blockIdx.x * 256 + threadIdx.x;
    s[threadIdx.x] = (i < n) ? deg[i] : 0u;
    __syncthreads();
    for (int st = 128; st > 0; st >>= 1) {
        if (threadIdx.x < st) s[threadIdx.x] += s[threadIdx.x + st];
        __syncthreads();
    }
    if (threadIdx.x == 0) bsum[blockIdx.x] = s[0];
}

__global__ void __launch_bounds__(512) k_scan_bsum(unsigned* __restrict__ bsum, int nb) {
    __shared__ unsigned s[512];
    int t = threadIdx.x;
    unsigned v0 = (t < nb) ? bsum[t] : 0u;
    s[t] = v0;
    __syncthreads();
    for (int off = 1; off < 512; off <<= 1) {
        unsigned v = (t >= off) ? s[t - off] : 0u;
        __syncthreads();
        s[t] += v;
        __syncthreads();
    }
    if (t < nb) bsum[t] = s[t] - v0;  // exclusive
}

// offsets + dinv + zero the degree buffer (it becomes the fill cursor)
__global__ void __launch_bounds__(256) k_offsets(unsigned* __restrict__ deg,
                                                 const unsigned* __restrict__ bsum,
                                                 unsigned* __restrict__ off,
                                                 float* __restrict__ dinv, int n) {
    __shared__ unsigned s[256];
    int t = threadIdx.x;
    int i = blockIdx.x * 256 + t;
    unsigned v0 = (i < n) ? deg[i] : 0u;
    s[t] = v0;
    __syncthreads();
    for (int o = 1; o < 256; o <<= 1) {
        unsigned v = (t >= o) ? s[t - o] : 0u;
        __syncthreads();
        s[t] += v;
        __syncthreads();
    }
    if (i < n) {
        off[i] = bsum[blockIdx.x] + s[t] - v0;
        dinv[i] = rsqrtf((float)(v0 + 1u));
        deg[i] = 0u;  // cursor for k_fill
    }
    if (i == n - 1) off[n] = bsum[blockIdx.x] + s[t];  // total = e
}

// ---------- CSR bucket fill (nt streaming reads keep csr lines in L2) --------
__global__ void k_fill(const int* __restrict__ src, const int* __restrict__ dst,
                       const unsigned* __restrict__ off, unsigned* __restrict__ cur,
                       int* __restrict__ csr, int e) {
    int j = blockIdx.x * blockDim.x + threadIdx.x;
    if (j < e) {
        int d = __builtin_nontemporal_load(&dst[j]);
        int s = __builtin_nontemporal_load(&src[j]);
        unsigned p = off[d] + atomicAdd(&cur[d], 1u);
        csr[p] = s;
    }
}

// ---------- GEMM1: t1w[n,16] = (x @ W1) * dinv[row] --------------------------
__global__ void __launch_bounds__(256) k_gemm1(const float* __restrict__ x,
                                               const float* __restrict__ W1,
                                               const float* __restrict__ dinv,
                                               float* __restrict__ t1w, int n) {
    __shared__ float ws[HID][260];  // transposed, padded
    for (int idx = threadIdx.x; idx < F_IN * HID; idx += 256) {
        int c = idx >> 4, k = idx & 15;
        ws[k][c] = W1[idx];
    }
    __syncthreads();
    int r = blockIdx.x * 16 + (threadIdx.x >> 4);
    int k = threadIdx.x & 15;
    if (r >= n) return;
    const f4v* xr = (const f4v*)(x + (size_t)r * F_IN);
    const f4v* wr = (const f4v*)&ws[k][0];
    float acc = 0.f;
#pragma unroll 8
    for (int c4 = 0; c4 < F_IN / 4; ++c4) {
        f4v v = __builtin_nontemporal_load(&xr[c4]);
        f4v w = wr[c4];
        acc += v[0] * w[0] + v[1] * w[1] + v[2] * w[2] + v[3] * w[3];
    }
    t1w[(size_t)r * HID + k] = acc * dinv[r];
}

// ---------- conv1 aggregation (gather) + bias + ReLU -------------------------
__global__ void __launch_bounds__(256) k_agg16(const int* __restrict__ csr,
                                               const unsigned* __restrict__ off,
                                               const float* __restrict__ t1w,
                                               const float* __restrict__ dinv,
                                               const float* __restrict__ b1,
                                               float* __restrict__ h, int n) {
    __shared__ float b1s[HID];
    if (threadIdx.x < HID) b1s[threadIdx.x] = b1[threadIdx.x];
    __syncthreads();
    int d = blockIdx.x * 16 + (threadIdx.x >> 4);
    int k = threadIdx.x & 15;
    if (d >= n) return;
    unsigned p = off[d], pe = off[d + 1];
    float acc = t1w[(size_t)d * HID + k];  // self loop
    for (; p + 1 < pe; p += 2) {
        int s0 = __builtin_nontemporal_load(&csr[p]);
        int s1 = __builtin_nontemporal_load(&csr[p + 1]);
        float v0 = t1w[(size_t)s0 * HID + k];
        float v1 = t1w[(size_t)s1 * HID + k];
        acc += v0 + v1;
    }
    if (p < pe) acc += t1w[(size_t)__builtin_nontemporal_load(&csr[p]) * HID + k];
    h[(size_t)d * HID + k] = fmaxf(acc * dinv[d] + b1s[k], 0.f);
}

// ---------- GEMM2: t2w[n,8] = (h @ W2) * dinv[row] ---------------------------
__global__ void __launch_bounds__(256) k_gemm2(const float* __restrict__ h,
                                               const float* __restrict__ W2,
                                               const float* __restrict__ dinv,
                                               float* __restrict__ t2w, int n) {
    __shared__ float w2s[HID * NCLS];
    if (threadIdx.x < HID * NCLS) w2s[threadIdx.x] = W2[threadIdx.x];
    __syncthreads();
    int i = blockIdx.x * blockDim.x + threadIdx.x;
    if (i >= n) return;
    float hv[HID];
    const f4v* h4 = (const f4v*)(h + (size_t)i * HID);
#pragma unroll
    for (int q = 0; q < 4; ++q) {
        f4v v = h4[q];
        hv[q * 4 + 0] = v[0]; hv[q * 4 + 1] = v[1];
        hv[q * 4 + 2] = v[2]; hv[q * 4 + 3] = v[3];
    }
    float o[NCLS];
#pragma unroll
    for (int c = 0; c < NCLS; ++c) o[c] = 0.f;
#pragma unroll
    for (int k = 0; k < HID; ++k)
#pragma unroll
        for (int c = 0; c < NCLS; ++c) o[c] += hv[k] * w2s[k * NCLS + c];
    float di = dinv[i];
    f4v* o4 = (f4v*)(t2w + (size_t)i * NCLS);
    f4v r0 = {o[0] * di, o[1] * di, o[2] * di, o[3] * di};
    f4v r1 = {o[4] * di, o[5] * di, o[6] * di, o[7] * di};
    o4[0] = r0;
    o4[1] = r1;
}

// ---------- conv2 aggregation (gather) + bias + fused mean-pool accumulate ---
__global__ void __launch_bounds__(256) k_agg8pool(const int* __restrict__ csr,
                                                  const unsigned* __restrict__ off,
                                                  const float* __restrict__ t2w,
                                                  const float* __restrict__ dinv,
                                                  const float* __restrict__ b2,
                                                  const int* __restrict__ batch,
                                                  float* __restrict__ out,
                                                  float* __restrict__ cg, int n) {
    __shared__ float wacc[WIN][NCLS];
    __shared__ float wcnt[WIN];
    __shared__ int gbase_s;
    int t = threadIdx.x;
    if (t < WIN * NCLS) ((float*)wacc)[t] = 0.f;
    if (t < WIN) wcnt[t] = 0.f;
    int b0 = blockIdx.x * 32;  // 32 dsts per block, 8 lanes each
    if (t == 0) gbase_s = batch[b0 < n ? b0 : (n - 1)];
    __syncthreads();
    int d = b0 + (t >> 3);
    int k = t & 7;
    int gbase = gbase_s;
    if (d < n) {
        unsigned p = off[d], pe = off[d + 1];
        float acc = t2w[(size_t)d * NCLS + k];  // self loop
        for (; p + 1 < pe; p += 2) {
            int s0 = __builtin_nontemporal_load(&csr[p]);
            int s1 = __builtin_nontemporal_load(&csr[p + 1]);
            float v0 = t2w[(size_t)s0 * NCLS + k];
            float v1 = t2w[(size_t)s1 * NCLS + k];
            acc += v0 + v1;
        }
        if (p < pe) acc += t2w[(size_t)__builtin_nontemporal_load(&csr[p]) * NCLS + k];
        float v = acc * dinv[d] + b2[k];
        int g = batch[d];
        if (g - gbase < WIN) {  // batch sorted => g >= gbase
            atomicAdd(&wacc[g - gbase][k], v);
            if (k == 0) atomicAdd(&wcnt[g - gbase], 1.f);
        } else {  // window overflow — rare fallback
            atomicAdd(&out[(size_t)g * NCLS + k], v);
            if (k == 0) atomicAdd(&cg[g], 1.f);
        }
    }
    __syncthreads();
    if (t < WIN * NCLS) {
        int gg = t >> 3, kk = t & 7;
        if (wcnt[gg] > 0.f) atomicAdd(&out[(size_t)(gbase + gg) * NCLS + kk], wacc[gg][kk]);
    }
    if (t < WIN && wcnt[t] > 0.f) atomicAdd(&cg[gbase + t], wcnt[t]);
}

__global__ void k_div(float* __restrict__ out, const float* __restrict__ cg, int total) {
    int i = blockIdx.x * blockDim.x + threadIdx.x;
    if (i < total) out[i] /= fmaxf(cg[i / NCLS], 1.0f);
}

extern "C" void kernel_launch(void* const* d_in, const int* in_sizes, int n_in,
                              void* d_out, int out_size, void* d_ws, size_t ws_size,
                              hipStream_t stream) {
    const float* x = (const float*)d_in[0];
    const int* ei = (const int*)d_in[1];
    const int* batch = (const int*)d_in[2];
    const float* W1 = (const float*)d_in[4];
    const float* b1 = (const float*)d_in[5];
    const float* W2 = (const float*)d_in[6];
    const float* b2 = (const float*)d_in[7];

    int n = in_sizes[0] / F_IN;
    int e = in_sizes[1] / 2;
    int g = out_size / NCLS;
    const int* src = ei;
    const int* dst = ei + e;
    int nb = (n + 255) / 256;

    char* w = (char*)d_ws;
    unsigned* degc = (unsigned*)w; w += (size_t)n * 4;   // degree, then fill-cursor
    float* dinv    = (float*)w;    w += (size_t)n * 4;
    unsigned* off  = (unsigned*)w; w += ((size_t)n + 1) * 4;
    unsigned* bsum = (unsigned*)w; w += (size_t)512 * 4;
    float* t1w     = (float*)w;    w += (size_t)n * HID * 4;
    float* hbuf    = (float*)w;    w += (size_t)n * HID * 4;
    float* t2w     = (float*)w;    w += (size_t)n * NCLS * 4;
    float* cg      = (float*)w;    w += (size_t)g * 4;
    int* csr       = (int*)w;      w += (size_t)e * 4;

    hipMemsetAsync(degc, 0, (size_t)n * 4, stream);
    hipMemsetAsync(cg, 0, (size_t)g * 4, stream);
    hipMemsetAsync(d_out, 0, (size_t)out_size * 4, stream);

    const int B = 256;
    k_deg<<<(e + B - 1) / B, B, 0, stream>>>(dst, e, degc);
    k_bsum<<<nb, 256, 0, stream>>>(degc, bsum, n);
    k_scan_bsum<<<1, 512, 0, stream>>>(bsum, nb);
    k_offsets<<<nb, 256, 0, stream>>>(degc, bsum, off, dinv, n);
    k_fill<<<(e + B - 1) / B, B, 0, stream>>>(src, dst, off, degc, csr, e);
    k_gemm1<<<(n + 15) / 16, 256, 0, stream>>>(x, W1, dinv, t1w, n);
    k_agg16<<<(n + 15) / 16, 256, 0, stream>>>(csr, off, t1w, dinv, b1, hbuf, n);
    k_gemm2<<<(n + B - 1) / B, B, 0, stream>>>(hbuf, W2, dinv, t2w, n);
    k_agg8pool<<<(n + 31) / 32, 256, 0, stream>>>(csr, off, t2w, dinv, b2, batch,
                                                  (float*)d_out, cg, n);
    k_div<<<(out_size + B - 1) / B, B, 0, stream>>>((float*)d_out, cg, out_size);
}